// Round 1
// baseline (1727.693 us; speedup 1.0000x reference)
//
#include <hip/hip_runtime.h>
#include <stdint.h>

#define D_MODEL 1024
#define NSEQ    4096
#define NVOCAB  50257
#define NVOCAB_PAD 50304

typedef float  f32x4  __attribute__((ext_vector_type(4)));
typedef __bf16 bf16x8 __attribute__((ext_vector_type(8)));

__device__ __forceinline__ unsigned short f32_to_bf16(float f) {
  union { float f; unsigned int u; } v; v.f = f;
  unsigned int u = v.u;
  unsigned int r = (u + 0x7fffu + ((u >> 16) & 1u)) >> 16;
  return (unsigned short)r;
}

__device__ __forceinline__ void load16_to_lds(const void* g, void* l) {
  __builtin_amdgcn_global_load_lds(
      (const __attribute__((address_space(1))) unsigned int*)g,
      (__attribute__((address_space(3))) unsigned int*)l,
      16, 0, 0);
}

// ---------------- gather + cast: x = bf16(E[tokens]) ----------------
__global__ void gather_cast(const int* __restrict__ tokens,
                            const float* __restrict__ E,
                            unsigned short* __restrict__ xb) {
  int i = blockIdx.x;
  int t = tokens[i];
  const float* src = E + (size_t)t * D_MODEL;
  unsigned short* dst = xb + (size_t)i * D_MODEL;
  int c = threadIdx.x * 4;  // 256 threads * 4 = 1024
  float4 a = *(const float4*)(src + c);
  ushort4 r;
  r.x = f32_to_bf16(a.x); r.y = f32_to_bf16(a.y);
  r.z = f32_to_bf16(a.z); r.w = f32_to_bf16(a.w);
  *(ushort4*)(dst + c) = r;
}

// ---------------- fp32 -> bf16 cast with zero-pad tail ----------------
__global__ void cast8(const float* __restrict__ src, unsigned short* __restrict__ dst,
                      long n, long ntot) {
  long i = ((long)blockIdx.x * blockDim.x + threadIdx.x) * 8;
  long stride = (long)gridDim.x * blockDim.x * 8;
  for (; i < ntot; i += stride) {
    ushort4 r0, r1;
    if (i < n) {  // n is a multiple of 8, so whole group is in-range
      float4 a = *(const float4*)(src + i);
      float4 b = *(const float4*)(src + i + 4);
      r0.x = f32_to_bf16(a.x); r0.y = f32_to_bf16(a.y);
      r0.z = f32_to_bf16(a.z); r0.w = f32_to_bf16(a.w);
      r1.x = f32_to_bf16(b.x); r1.y = f32_to_bf16(b.y);
      r1.z = f32_to_bf16(b.z); r1.w = f32_to_bf16(b.w);
    } else {
      r0.x = r0.y = r0.z = r0.w = 0;
      r1.x = r1.y = r1.z = r1.w = 0;
    }
    *(ushort4*)(dst + i) = r0;
    *(ushort4*)(dst + i + 4) = r1;
  }
}

// ---------------- pack bq|bk|bv into one [3072] fp32 ----------------
__global__ void pack_bias(const float* __restrict__ bq, const float* __restrict__ bk,
                          const float* __restrict__ bv, float* __restrict__ out) {
  int i = blockIdx.x * 256 + threadIdx.x;
  if (i < 1024)       out[i] = bq[i];
  else if (i < 2048)  out[i] = bk[i - 1024];
  else if (i < 3072)  out[i] = bv[i - 2048];
}

// ---------------- transpose V [4096,1024](stride 3072) -> Vt [1024,4096] ----------------
__global__ void transpose_v(const unsigned short* __restrict__ V,
                            unsigned short* __restrict__ Vt) {
  __shared__ unsigned short tile[64][68];
  int j0 = blockIdx.x * 64;   // sequence block
  int d0 = blockIdx.y * 64;   // feature block
  int tx = threadIdx.x & 15;
  int ty = threadIdx.x >> 4;
#pragma unroll
  for (int p = 0; p < 4; ++p) {
    int r = ty + p * 16;
    ushort4 v = *(const ushort4*)&V[(size_t)(j0 + r) * 3072 + d0 + tx * 4];
    tile[r][tx * 4 + 0] = v.x; tile[r][tx * 4 + 1] = v.y;
    tile[r][tx * 4 + 2] = v.z; tile[r][tx * 4 + 3] = v.w;
  }
  __syncthreads();
#pragma unroll
  for (int p = 0; p < 4; ++p) {
    int r = ty + p * 16;
    ushort4 w;
    w.x = tile[tx * 4 + 0][r]; w.y = tile[tx * 4 + 1][r];
    w.z = tile[tx * 4 + 2][r]; w.w = tile[tx * 4 + 3][r];
    *(ushort4*)&Vt[(size_t)(d0 + r) * 4096 + j0 + tx * 4] = w;
  }
}

// ---------------- causal row softmax: S fp32 -> P bf16 (zeros for j>i) ----------------
__global__ void softmax_causal(const float* __restrict__ S,
                               unsigned short* __restrict__ P, float scale) {
  int i = blockIdx.x;
  int n = i + 1;
  const float* row = S + (size_t)i * NSEQ;
  unsigned short* prow = P + (size_t)i * NSEQ;
  int tid = threadIdx.x;
  __shared__ float redm[4];
  __shared__ float reds[4];

  float m = -1e30f;
  for (int j = tid; j < n; j += 256) m = fmaxf(m, row[j] * scale);
#pragma unroll
  for (int o = 32; o > 0; o >>= 1) m = fmaxf(m, __shfl_down(m, o, 64));
  if ((tid & 63) == 0) redm[tid >> 6] = m;
  __syncthreads();
  m = fmaxf(fmaxf(redm[0], redm[1]), fmaxf(redm[2], redm[3]));

  float s = 0.f;
  for (int j = tid; j < n; j += 256) s += __expf(row[j] * scale - m);
#pragma unroll
  for (int o = 32; o > 0; o >>= 1) s += __shfl_down(s, o, 64);
  if ((tid & 63) == 0) reds[tid >> 6] = s;
  __syncthreads();
  s = reds[0] + reds[1] + reds[2] + reds[3];
  float inv = 1.0f / s;

  for (int j = tid; j < NSEQ; j += 256) {
    float v = (j < n) ? __expf(row[j] * scale - m) * inv : 0.0f;
    prow[j] = f32_to_bf16(v);
  }
}

// ---------------- NT GEMM: C[m,n] = scale*sum_k A[m,k]*B[n,k] (+bias[n]) ----------------
// m97 structure: 128x128 tile, BK=32, 4 waves each computing 64x64,
// global_load_lds width-16 staging, 16x16x32 bf16 MFMA.
#define BM 128
#define BN 128
#define BK 32

template<int SB /*store bf16*/, int HASBIAS, int CSKIP, int KTRIM, int NB /*n bounds*/>
__launch_bounds__(256, 2)
__global__ void gemm_nt(const unsigned short* __restrict__ A,
                        const unsigned short* __restrict__ B,
                        const float* __restrict__ bias,
                        void* __restrict__ Cv,
                        int M, int N, int K,
                        long lda, long ldb, long ldc, float scale) {
  int m0 = blockIdx.x * BM;
  int n0 = blockIdx.y * BN;
  if (CSKIP && n0 > m0) return;   // block strictly above causal diagonal

  __shared__ __align__(16) unsigned short As[BM * BK];
  __shared__ __align__(16) unsigned short Bs[BN * BK];

  int tid  = threadIdx.x;
  int wave = tid >> 6;
  int lane = tid & 63;
  int l15  = lane & 15;
  int quad = lane >> 4;
  int wm   = (wave >> 1) * 64;
  int wn   = (wave & 1) * 64;

  f32x4 zero = {0.f, 0.f, 0.f, 0.f};
  f32x4 acc[4][4];
#pragma unroll
  for (int i = 0; i < 4; i++)
#pragma unroll
    for (int j = 0; j < 4; j++) acc[i][j] = zero;

  int kEnd = K;
  if (KTRIM) { int ke = m0 + BM; kEnd = ke < K ? ke : K; }

  for (int kt = 0; kt < kEnd; kt += BK) {
    // ---- stage 16 KB (A + B tiles) via async global->LDS, 16 B/lane ----
#pragma unroll
    for (int c = 0; c < 2; ++c) {
      int base = wave * 2048 + c * 1024;       // bytes, wave-uniform LDS base
      int e    = (base + lane * 16) >> 1;      // element index of this lane's chunk
      int row  = e >> 5;                       // /32 (BK)
      int col  = e & 31;
      load16_to_lds(A + (size_t)(m0 + row) * lda + kt + col, (char*)As + base);
      load16_to_lds(B + (size_t)(n0 + row) * ldb + kt + col, (char*)Bs + base);
    }
    __syncthreads();
    // ---- compute: 16 MFMA per wave ----
    bf16x8 af[4], bf[4];
#pragma unroll
    for (int i = 0; i < 4; i++)
      af[i] = *(const bf16x8*)&As[(wm + i * 16 + l15) * BK + quad * 8];
#pragma unroll
    for (int j = 0; j < 4; j++)
      bf[j] = *(const bf16x8*)&Bs[(wn + j * 16 + l15) * BK + quad * 8];
#pragma unroll
    for (int i = 0; i < 4; i++)
#pragma unroll
      for (int j = 0; j < 4; j++)
        acc[i][j] = __builtin_amdgcn_mfma_f32_16x16x32_bf16(af[i], bf[j], acc[i][j], 0, 0, 0);
    __syncthreads();
  }

  // ---- epilogue: D row = quad*4+r, col = lane&15 (verified m89/m91 layout) ----
#pragma unroll
  for (int i = 0; i < 4; i++) {
#pragma unroll
    for (int j = 0; j < 4; j++) {
      int col = n0 + wn + j * 16 + l15;
      if (NB && col >= N) continue;
      float bv = HASBIAS ? bias[col] : 0.0f;
#pragma unroll
      for (int r = 0; r < 4; r++) {
        int row = m0 + wm + i * 16 + quad * 4 + r;
        float v = acc[i][j][r] * scale + bv;
        if (SB)
          ((unsigned short*)Cv)[(size_t)row * ldc + col] = f32_to_bf16(v);
        else
          ((float*)Cv)[(size_t)row * ldc + col] = v;
      }
    }
  }
}

extern "C" void kernel_launch(void* const* d_in, const int* in_sizes, int n_in,
                              void* d_out, int out_size, void* d_ws, size_t ws_size,
                              hipStream_t stream) {
  const int*   tokens = (const int*)d_in[0];
  const float* E  = (const float*)d_in[1];
  const float* Wq = (const float*)d_in[2];
  const float* bq = (const float*)d_in[3];
  const float* Wk = (const float*)d_in[4];
  const float* bk = (const float*)d_in[5];
  const float* Wv = (const float*)d_in[6];
  const float* bv = (const float*)d_in[7];
  const float* Wp = (const float*)d_in[8];
  const float* bp = (const float*)d_in[9];
  float* out = (float*)d_out;

  // workspace layout (all chunks multiple-of-1024 bytes -> 16B aligned)
  char* ws = (char*)d_ws;
  unsigned short* xb    = (unsigned short*)ws;                      // [4096,1024] bf16
  unsigned short* Wqkvb = xb + (size_t)NSEQ * D_MODEL;              // [3072,1024] bf16
  unsigned short* Wpb   = Wqkvb + (size_t)3 * D_MODEL * D_MODEL;    // [50304,1024] bf16
  float*          bqkv  = (float*)(Wpb + (size_t)NVOCAB_PAD * D_MODEL); // [3072] fp32
  unsigned short* QKVb  = (unsigned short*)(bqkv + 3 * D_MODEL);    // [4096,3072] bf16
  unsigned short* Vt    = QKVb + (size_t)NSEQ * 3 * D_MODEL;        // [1024,4096] bf16
  float*          S     = (float*)(Vt + (size_t)D_MODEL * NSEQ);    // [4096,4096] fp32
  unsigned short* P     = (unsigned short*)(S + (size_t)NSEQ * NSEQ);// [4096,4096] bf16
  unsigned short* outb  = P + (size_t)NSEQ * NSEQ;                  // [4096,1024] bf16

  // 1) gather + casts
  gather_cast<<<NSEQ, 256, 0, stream>>>(tokens, E, xb);
  long MB1 = (long)D_MODEL * D_MODEL;
  cast8<<<(int)((MB1/8 + 255)/256), 256, 0, stream>>>(Wq, Wqkvb,           MB1, MB1);
  cast8<<<(int)((MB1/8 + 255)/256), 256, 0, stream>>>(Wk, Wqkvb + MB1,     MB1, MB1);
  cast8<<<(int)((MB1/8 + 255)/256), 256, 0, stream>>>(Wv, Wqkvb + 2 * MB1, MB1, MB1);
  long np  = (long)NVOCAB * D_MODEL;
  long npt = (long)NVOCAB_PAD * D_MODEL;
  cast8<<<(int)((npt/8 + 255)/256), 256, 0, stream>>>(Wp, Wpb, np, npt);
  pack_bias<<<12, 256, 0, stream>>>(bq, bk, bv, bqkv);

  // 2) fused QKV projection: [4096,3072] = xb @ Wqkv^T + bqkv
  gemm_nt<1,1,0,0,0><<<dim3(NSEQ/BM, 3*D_MODEL/BN), 256, 0, stream>>>(
      xb, Wqkvb, bqkv, QKVb, NSEQ, 3*D_MODEL, D_MODEL,
      D_MODEL, D_MODEL, 3*D_MODEL, 1.0f);

  // 3) S = Q @ K^T (fp32, lower-triangular blocks only)
  gemm_nt<0,0,1,0,0><<<dim3(NSEQ/BM, NSEQ/BN), 256, 0, stream>>>(
      QKVb, QKVb + D_MODEL, nullptr, S, NSEQ, NSEQ, D_MODEL,
      3*D_MODEL, 3*D_MODEL, NSEQ, 1.0f);

  // 4) causal softmax rows (scale 1/sqrt(1024) = 1/32), P bf16 zero-filled above diag
  softmax_causal<<<NSEQ, 256, 0, stream>>>(S, P, 0.03125f);

  // 5) V^T for the PV GEMM
  transpose_v<<<dim3(NSEQ/64, D_MODEL/64), 256, 0, stream>>>(QKVb + 2*D_MODEL, Vt);

  // 6) out = P @ V  (K-loop trimmed to causal extent)
  gemm_nt<1,0,0,1,0><<<dim3(NSEQ/BM, D_MODEL/BN), 256, 0, stream>>>(
      P, Vt, nullptr, outb, NSEQ, D_MODEL, NSEQ,
      NSEQ, NSEQ, D_MODEL, 1.0f);

  // 7) logits = out @ Wp^T + bp  (N=50257, bounds-guarded)
  gemm_nt<0,1,0,0,1><<<dim3(NSEQ/BM, (NVOCAB + BN - 1)/BN), 256, 0, stream>>>(
      outb, Wpb, bp, out, NSEQ, NVOCAB, D_MODEL,
      D_MODEL, D_MODEL, NVOCAB, 1.0f);
}